// Round 1
// baseline (265.810 us; speedup 1.0000x reference)
//
#include <hip/hip_runtime.h>
#include <hip/hip_fp16.h>

#define NN 4
#define CC 256
#define PP 2304   // 48*48
#define EPSV 1e-5f

typedef __attribute__((ext_vector_type(8))) short bf16x8;
typedef __attribute__((ext_vector_type(4))) float f32x4;

// monotone float<->uint encoding so uint atomicMin == float min (handles negatives)
__device__ inline unsigned fenc(float f) {
  unsigned b = __float_as_uint(f);
  return (b & 0x80000000u) ? ~b : (b | 0x80000000u);
}
__device__ inline float fdec(unsigned e) {
  unsigned b = (e & 0x80000000u) ? (e ^ 0x80000000u) : ~e;
  return __uint_as_float(b);
}

__device__ inline unsigned short f2bf(float x) {  // RNE float->bf16
  unsigned u = __float_as_uint(x);
  unsigned r = (u + 0x7FFFu + ((u >> 16) & 1u)) >> 16;
  return (unsigned short)r;
}

// Kernel 1: per-channel mean of featureT over (N,H,W); also init scratch
__global__ __launch_bounds__(256) void k_mean(const float* __restrict__ fT,
                                              float* __restrict__ meanT,
                                              unsigned* __restrict__ divu,
                                              float* __restrict__ S,
                                              float* __restrict__ cxsum) {
  int c = blockIdx.x, t = threadIdx.x;
  float s = 0.f;
  for (int n = 0; n < NN; n++) {
    const float* base = fT + (size_t)n * CC * PP + (size_t)c * PP;
    for (int p = t; p < PP; p += 256) s += base[p];
  }
  for (int o = 32; o > 0; o >>= 1) s += __shfl_down(s, o);
  __shared__ float red[4];
  if ((t & 63) == 0) red[t >> 6] = s;
  __syncthreads();
  if (t == 0) meanT[c] = (red[0] + red[1] + red[2] + red[3]) / (float)(NN * PP);
  // init div (encoded +inf = 0xFFFFFFFF) and S=0: 9216 entries = 256 blocks * 36
  if (t < 36) {
    int idx = c * 36 + t;
    divu[idx] = 0xFFFFFFFFu;
    S[idx] = 0.f;
  }
  if (blockIdx.x == 0 && t < 4) cxsum[t] = 0.f;
}

// Kernel 2: center by meanT, l2-normalize over C, transpose to [N][P][C] bf16
__global__ __launch_bounds__(256) void k_norm(const float* __restrict__ fT,
                                              const float* __restrict__ fI,
                                              const float* __restrict__ meanT,
                                              unsigned short* __restrict__ A,
                                              unsigned short* __restrict__ B) {
  int n = blockIdx.y;
  int p0 = blockIdx.x * 16;
  int t = threadIdx.x;
  int tc = t >> 4, tp = t & 15;
  __shared__ float cT[16][257];
  __shared__ float cI[16][257];
  __shared__ float redT[16][17], redI[16][17];
  __shared__ float inv[2][16];
  float aT = 0.f, aI = 0.f;
  int p = p0 + tp;
  for (int c0 = 0; c0 < CC; c0 += 16) {
    int c = c0 + tc;
    float m = meanT[c];
    size_t g = (size_t)n * CC * PP + (size_t)c * PP + p;
    float vT = fT[g] - m;
    float vI = fI[g] - m;
    cT[tp][c] = vT; cI[tp][c] = vI;
    aT += vT * vT; aI += vI * vI;
  }
  redT[tp][tc] = aT; redI[tp][tc] = aI;
  __syncthreads();
  if (t < 16) {
    float sT = 0.f, sI = 0.f;
    for (int k = 0; k < 16; k++) { sT += redT[t][k]; sI += redI[t][k]; }
    inv[0][t] = 1.0f / sqrtf(sT);
    inv[1][t] = 1.0f / sqrtf(sI);
  }
  __syncthreads();
  for (int pp = 0; pp < 16; pp++) {
    size_t o = ((size_t)(n * PP + p0 + pp)) * CC + t;
    A[o] = f2bf(cT[pp][t] * inv[0][pp]);
    B[o] = f2bf(cI[pp][t] * inv[1][pp]);
  }
}

// Kernel 3: per-sample GEMM G = A·B^T via MFMA bf16; write raw=(1-G)/2 fp16;
// fused column-min (over rows i) into divu via encoded atomicMin
__global__ __launch_bounds__(256) void k_gemm(const unsigned short* __restrict__ A,
                                              const unsigned short* __restrict__ B,
                                              __half* __restrict__ raw,
                                              unsigned* __restrict__ divu) {
  int n  = blockIdx.z;
  int i0 = blockIdx.y * 64;
  int j0 = blockIdx.x * 64;
  int t  = threadIdx.x;
  int lane = t & 63;
  int w = t >> 6;
  int wi = w >> 1, wj = w & 1;
  int lr = lane & 15, lq = lane >> 4;

  __shared__ unsigned short As[64][40];  // pad 32->40 shorts (80B rows) for banks
  __shared__ unsigned short Bs[64][40];
  __shared__ unsigned cmin[64];
  if (t < 64) cmin[t] = 0xFFFFFFFFu;

  f32x4 acc[2][2];
#pragma unroll
  for (int a = 0; a < 2; a++)
#pragma unroll
    for (int b = 0; b < 2; b++) acc[a][b] = (f32x4){0.f, 0.f, 0.f, 0.f};

  int row = t >> 2, seg = t & 3;
  const size_t baseA = ((size_t)(n * PP + i0 + row)) * CC;
  const size_t baseB = ((size_t)(n * PP + j0 + row)) * CC;

  for (int k0 = 0; k0 < CC; k0 += 32) {
    if (k0) __syncthreads();
    int4 va = *(const int4*)(A + baseA + k0 + seg * 8);
    int4 vb = *(const int4*)(B + baseB + k0 + seg * 8);
    *(int4*)&As[row][seg * 8] = va;
    *(int4*)&Bs[row][seg * 8] = vb;
    __syncthreads();
    bf16x8 a0 = *(const bf16x8*)&As[wi * 32 + lr][lq * 8];
    bf16x8 a1 = *(const bf16x8*)&As[wi * 32 + 16 + lr][lq * 8];
    bf16x8 b0 = *(const bf16x8*)&Bs[wj * 32 + lr][lq * 8];
    bf16x8 b1 = *(const bf16x8*)&Bs[wj * 32 + 16 + lr][lq * 8];
    acc[0][0] = __builtin_amdgcn_mfma_f32_16x16x32_bf16(a0, b0, acc[0][0], 0, 0, 0);
    acc[0][1] = __builtin_amdgcn_mfma_f32_16x16x32_bf16(a0, b1, acc[0][1], 0, 0, 0);
    acc[1][0] = __builtin_amdgcn_mfma_f32_16x16x32_bf16(a1, b0, acc[1][0], 0, 0, 0);
    acc[1][1] = __builtin_amdgcn_mfma_f32_16x16x32_bf16(a1, b1, acc[1][1], 0, 0, 0);
  }

  // epilogue: C/D layout col=lane&15, row=(lane>>4)*4+reg  [m89/m91 verified]
#pragma unroll
  for (int tj = 0; tj < 2; tj++) {
    float mx = -1e30f;
    int gj = j0 + wj * 32 + tj * 16 + lr;
#pragma unroll
    for (int ti = 0; ti < 2; ti++) {
#pragma unroll
      for (int r = 0; r < 4; r++) {
        float g = acc[ti][tj][r];
        mx = fmaxf(mx, g);
        int gi = i0 + wi * 32 + ti * 16 + lq * 4 + r;
        raw[((size_t)n * PP + gi) * PP + gj] = __float2half((1.0f - g) * 0.5f);
      }
    }
    float rmin = (1.0f - mx) * 0.5f;  // min raw == (1 - max G)/2
    atomicMin(&cmin[wj * 32 + tj * 16 + lr], fenc(rmin));
  }
  __syncthreads();
  if (t < 64) atomicMin(&divu[n * PP + j0 + t], cmin[t]);
}

// Kernel 4: column sums S_j = sum_i exp(-10*raw[i][j]/(div_j+eps))
__global__ __launch_bounds__(256) void k_colsum(const __half* __restrict__ raw,
                                                const unsigned* __restrict__ divu,
                                                float* __restrict__ S) {
  int n = blockIdx.y;
  int j0 = blockIdx.x * 64;
  int rz = blockIdx.z;
  int t = threadIdx.x;
  int jc = t & 63, w = t >> 6;
  float d = fdec(divu[n * PP + j0 + jc]);
  float scale = -10.0f / (d + EPSV);
  const __half* base = raw + (size_t)n * PP * PP;
  float s = 0.f;
  for (int i = rz * 288 + w; i < (rz + 1) * 288; i += 4)
    s += __expf(0.f) * 0.f + expf(__half2float(base[(size_t)i * PP + j0 + jc]) * scale);
  __shared__ float red[4][64];
  red[w][jc] = s;
  __syncthreads();
  if (t < 64) atomicAdd(&S[n * PP + j0 + t], red[0][t] + red[1][t] + red[2][t] + red[3][t]);
}

// Kernel 5: per-row max of exp(l)/S_j, accumulate mean into cxsum[n]
__global__ __launch_bounds__(256) void k_rowmax(const __half* __restrict__ raw,
                                                const unsigned* __restrict__ divu,
                                                const float* __restrict__ S,
                                                float* __restrict__ cxsum) {
  int i = blockIdx.x, n = blockIdx.y, t = threadIdx.x;
  const __half* base = raw + ((size_t)n * PP + i) * PP;
  float m = 0.f;
  for (int j = t; j < PP; j += 256) {
    float d = fdec(divu[n * PP + j]);
    float scale = -10.0f / (d + EPSV);
    float wv = expf(__half2float(base[j]) * scale);
    m = fmaxf(m, wv / S[n * PP + j]);
  }
  for (int o = 32; o > 0; o >>= 1) m = fmaxf(m, __shfl_down(m, o));
  __shared__ float red[4];
  if ((t & 63) == 0) red[t >> 6] = m;
  __syncthreads();
  if (t == 0) {
    float mm = fmaxf(fmaxf(red[0], red[1]), fmaxf(red[2], red[3]));
    atomicAdd(&cxsum[n], mm * (1.0f / (float)PP));
  }
}

// Kernel 6: CX_B = -log(cxsum), loss = mean
__global__ void k_final(const float* __restrict__ cxsum, float* __restrict__ out) {
  int t = threadIdx.x;
  float cxb = 0.f;
  if (t < 4) {
    cxb = -logf(cxsum[t]);
    out[1 + t] = cxb;
  }
  for (int o = 2; o > 0; o >>= 1) cxb += __shfl_down(cxb, o);
  if (t == 0) out[0] = cxb * 0.25f;
}

extern "C" void kernel_launch(void* const* d_in, const int* in_sizes, int n_in,
                              void* d_out, int out_size, void* d_ws, size_t ws_size,
                              hipStream_t stream) {
  const float* fT = (const float*)d_in[0];
  const float* fI = (const float*)d_in[1];
  float* out = (float*)d_out;

  char* w = (char*)d_ws;
  float* meanT   = (float*)w;                                    // 1024 B
  unsigned* divu = (unsigned*)(w + 1024);                        // 36864 B
  float* S       = (float*)(w + 1024 + 36864);                   // 36864 B
  float* cxsum   = (float*)(w + 1024 + 2 * 36864);               // pad to 1024
  size_t off = 1024 + 2 * 36864 + 1024;                          // 75776
  unsigned short* A = (unsigned short*)(w + off);                // 4718592 B
  unsigned short* B = (unsigned short*)(w + off + 4718592);      // 4718592 B
  __half* raw = (__half*)(w + off + 2 * 4718592);                // 42467328 B

  k_mean<<<256, 256, 0, stream>>>(fT, meanT, divu, S, cxsum);
  k_norm<<<dim3(PP / 16, NN), 256, 0, stream>>>(fT, fI, meanT, A, B);
  k_gemm<<<dim3(PP / 64, PP / 64, NN), 256, 0, stream>>>(A, B, raw, divu);
  k_colsum<<<dim3(PP / 64, NN, 8), 256, 0, stream>>>(raw, divu, S);
  k_rowmax<<<dim3(PP, NN), 256, 0, stream>>>(raw, divu, S, cxsum);
  k_final<<<1, 64, 0, stream>>>(cxsum, out);
}

// Round 2
// 200.726 us; speedup vs baseline: 1.3242x; 1.3242x over previous
//
#include <hip/hip_runtime.h>
#include <hip/hip_fp16.h>

#define NN 4
#define CC 256
#define PP 2304   // 48*48
#define EPSV 1e-5f

typedef __attribute__((ext_vector_type(8))) short bf16x8;
typedef __attribute__((ext_vector_type(4))) float f32x4;

struct alignas(8) h4 { __half2 a, b; };

// monotone float<->uint encoding so uint atomicMin == float min (handles negatives)
__device__ inline unsigned fenc(float f) {
  unsigned b = __float_as_uint(f);
  return (b & 0x80000000u) ? ~b : (b | 0x80000000u);
}
__device__ inline float fdec(unsigned e) {
  unsigned b = (e & 0x80000000u) ? (e ^ 0x80000000u) : ~e;
  return __uint_as_float(b);
}

__device__ inline unsigned short f2bf(float x) {  // RNE float->bf16
  unsigned u = __float_as_uint(x);
  unsigned r = (u + 0x7FFFu + ((u >> 16) & 1u)) >> 16;
  return (unsigned short)r;
}

// Kernel 1: per-channel mean of featureT over (N,H,W); also init scratch
__global__ __launch_bounds__(256) void k_mean(const float* __restrict__ fT,
                                              float* __restrict__ meanT,
                                              unsigned* __restrict__ divu,
                                              float* __restrict__ S,
                                              float* __restrict__ cxsum) {
  int c = blockIdx.x, t = threadIdx.x;
  float s = 0.f;
  for (int n = 0; n < NN; n++) {
    const float* base = fT + (size_t)n * CC * PP + (size_t)c * PP;
    for (int p = t; p < PP; p += 256) s += base[p];
  }
  for (int o = 32; o > 0; o >>= 1) s += __shfl_down(s, o);
  __shared__ float red[4];
  if ((t & 63) == 0) red[t >> 6] = s;
  __syncthreads();
  if (t == 0) meanT[c] = (red[0] + red[1] + red[2] + red[3]) / (float)(NN * PP);
  // init div (encoded +inf = 0xFFFFFFFF) and S=0: 9216 entries = 256 blocks * 36
  if (t < 36) {
    int idx = c * 36 + t;
    divu[idx] = 0xFFFFFFFFu;
    S[idx] = 0.f;
  }
  if (blockIdx.x == 0 && t < 4) cxsum[t] = 0.f;
}

// Kernel 2: center by meanT, l2-normalize over C, transpose to [N][P][C] bf16
__global__ __launch_bounds__(256) void k_norm(const float* __restrict__ fT,
                                              const float* __restrict__ fI,
                                              const float* __restrict__ meanT,
                                              unsigned short* __restrict__ A,
                                              unsigned short* __restrict__ B) {
  int n = blockIdx.y;
  int p0 = blockIdx.x * 16;
  int t = threadIdx.x;
  int tc = t >> 4, tp = t & 15;
  __shared__ float cT[16][257];
  __shared__ float cI[16][257];
  __shared__ float redT[16][17], redI[16][17];
  __shared__ float inv[2][16];
  float aT = 0.f, aI = 0.f;
  int p = p0 + tp;
  for (int c0 = 0; c0 < CC; c0 += 16) {
    int c = c0 + tc;
    float m = meanT[c];
    size_t g = (size_t)n * CC * PP + (size_t)c * PP + p;
    float vT = fT[g] - m;
    float vI = fI[g] - m;
    cT[tp][c] = vT; cI[tp][c] = vI;
    aT += vT * vT; aI += vI * vI;
  }
  redT[tp][tc] = aT; redI[tp][tc] = aI;
  __syncthreads();
  if (t < 16) {
    float sT = 0.f, sI = 0.f;
    for (int k = 0; k < 16; k++) { sT += redT[t][k]; sI += redI[t][k]; }
    inv[0][t] = 1.0f / sqrtf(sT);
    inv[1][t] = 1.0f / sqrtf(sI);
  }
  __syncthreads();
  for (int pp = 0; pp < 16; pp++) {
    size_t o = ((size_t)(n * PP + p0 + pp)) * CC + t;
    A[o] = f2bf(cT[pp][t] * inv[0][pp]);
    B[o] = f2bf(cI[pp][t] * inv[1][pp]);
  }
}

// Kernel 3: per-sample GEMM G = A·B^T via MFMA bf16; write raw=(1-G)/2 fp16;
// fused column-min (over rows i) into divu via encoded atomicMin
__global__ __launch_bounds__(256) void k_gemm(const unsigned short* __restrict__ A,
                                              const unsigned short* __restrict__ B,
                                              __half* __restrict__ raw,
                                              unsigned* __restrict__ divu) {
  int n  = blockIdx.z;
  int i0 = blockIdx.y * 64;
  int j0 = blockIdx.x * 64;
  int t  = threadIdx.x;
  int lane = t & 63;
  int w = t >> 6;
  int wi = w >> 1, wj = w & 1;
  int lr = lane & 15, lq = lane >> 4;

  __shared__ unsigned short As[64][40];  // pad 32->40 shorts (80B rows) for banks
  __shared__ unsigned short Bs[64][40];
  __shared__ unsigned cmin[64];
  if (t < 64) cmin[t] = 0xFFFFFFFFu;

  f32x4 acc[2][2];
#pragma unroll
  for (int a = 0; a < 2; a++)
#pragma unroll
    for (int b = 0; b < 2; b++) acc[a][b] = (f32x4){0.f, 0.f, 0.f, 0.f};

  int row = t >> 2, seg = t & 3;
  const size_t baseA = ((size_t)(n * PP + i0 + row)) * CC;
  const size_t baseB = ((size_t)(n * PP + j0 + row)) * CC;

  for (int k0 = 0; k0 < CC; k0 += 32) {
    if (k0) __syncthreads();
    int4 va = *(const int4*)(A + baseA + k0 + seg * 8);
    int4 vb = *(const int4*)(B + baseB + k0 + seg * 8);
    *(int4*)&As[row][seg * 8] = va;
    *(int4*)&Bs[row][seg * 8] = vb;
    __syncthreads();
    bf16x8 a0 = *(const bf16x8*)&As[wi * 32 + lr][lq * 8];
    bf16x8 a1 = *(const bf16x8*)&As[wi * 32 + 16 + lr][lq * 8];
    bf16x8 b0 = *(const bf16x8*)&Bs[wj * 32 + lr][lq * 8];
    bf16x8 b1 = *(const bf16x8*)&Bs[wj * 32 + 16 + lr][lq * 8];
    acc[0][0] = __builtin_amdgcn_mfma_f32_16x16x32_bf16(a0, b0, acc[0][0], 0, 0, 0);
    acc[0][1] = __builtin_amdgcn_mfma_f32_16x16x32_bf16(a0, b1, acc[0][1], 0, 0, 0);
    acc[1][0] = __builtin_amdgcn_mfma_f32_16x16x32_bf16(a1, b0, acc[1][0], 0, 0, 0);
    acc[1][1] = __builtin_amdgcn_mfma_f32_16x16x32_bf16(a1, b1, acc[1][1], 0, 0, 0);
  }

  // epilogue: C/D layout col=lane&15, row=(lane>>4)*4+reg  [m89/m91 verified]
#pragma unroll
  for (int tj = 0; tj < 2; tj++) {
    float mx = -1e30f;
    int gj = j0 + wj * 32 + tj * 16 + lr;
#pragma unroll
    for (int ti = 0; ti < 2; ti++) {
#pragma unroll
      for (int r = 0; r < 4; r++) {
        float g = acc[ti][tj][r];
        mx = fmaxf(mx, g);
        int gi = i0 + wi * 32 + ti * 16 + lq * 4 + r;
        raw[((size_t)n * PP + gi) * PP + gj] = __float2half((1.0f - g) * 0.5f);
      }
    }
    float rmin = (1.0f - mx) * 0.5f;  // min raw == (1 - max G)/2
    atomicMin(&cmin[wj * 32 + tj * 16 + lr], fenc(rmin));
  }
  __syncthreads();
  if (t < 64) atomicMin(&divu[n * PP + j0 + t], cmin[t]);
}

// Kernel 4: column sums S_j = sum_i exp(scale_j * raw[i][j]); scale from divu.
// Vectorized: 4 cols/lane (8B half loads), 4 waves split rows, z splits rows x4.
__global__ __launch_bounds__(256) void k_colsum(const __half* __restrict__ raw,
                                                const unsigned* __restrict__ divu,
                                                float* __restrict__ S) {
  int n = blockIdx.y;
  int j0 = blockIdx.x * 256;       // 9 blocks in x
  int rz = blockIdx.z;             // 4 chunks of 576 rows
  int t = threadIdx.x;
  int lane = t & 63, w = t >> 6;
  int j = j0 + lane * 4;

  uint4 dv = *(const uint4*)(divu + n * PP + j);
  float4 sc;
  sc.x = -10.0f / (fdec(dv.x) + EPSV);
  sc.y = -10.0f / (fdec(dv.y) + EPSV);
  sc.z = -10.0f / (fdec(dv.z) + EPSV);
  sc.w = -10.0f / (fdec(dv.w) + EPSV);

  const __half* base = raw + (size_t)n * PP * PP;
  float4 s = {0.f, 0.f, 0.f, 0.f};
  int i0 = rz * 576;
  for (int i = i0 + w; i < i0 + 576; i += 4) {
    h4 hv = *(const h4*)(base + (size_t)i * PP + j);
    float2 f01 = __half22float2(hv.a);
    float2 f23 = __half22float2(hv.b);
    s.x += __expf(f01.x * sc.x);
    s.y += __expf(f01.y * sc.y);
    s.z += __expf(f23.x * sc.z);
    s.w += __expf(f23.y * sc.w);
  }
  __shared__ float4 red4[4][64];
  red4[w][lane] = s;
  __syncthreads();
  if (t < 64) {
    float4 a = red4[0][t], b = red4[1][t], c = red4[2][t], d = red4[3][t];
    int jj = j0 + t * 4;
    atomicAdd(&S[n * PP + jj + 0], a.x + b.x + c.x + d.x);
    atomicAdd(&S[n * PP + jj + 1], a.y + b.y + c.y + d.y);
    atomicAdd(&S[n * PP + jj + 2], a.z + b.z + c.z + d.z);
    atomicAdd(&S[n * PP + jj + 3], a.w + b.w + c.w + d.w);
  }
}

// Kernel 4.5: per-column scale_j and ln(S_j)
__global__ __launch_bounds__(256) void k_logscale(const unsigned* __restrict__ divu,
                                                  const float* __restrict__ S,
                                                  float* __restrict__ scale,
                                                  float* __restrict__ lnS) {
  int i = blockIdx.x * 256 + threadIdx.x;  // 36 blocks cover 9216
  float d = fdec(divu[i]);
  scale[i] = -10.0f / (d + EPSV);
  lnS[i] = logf(S[i]);
}

// Kernel 5: per-row max of (scale_j*raw - lnS_j); CX[p]=exp(max); mean into cxsum.
// One wave per row; 8B half loads + 16B float loads. exp/div-free inner loop.
__global__ __launch_bounds__(256) void k_rowmax(const __half* __restrict__ raw,
                                                const float* __restrict__ scale,
                                                const float* __restrict__ lnS,
                                                float* __restrict__ cxsum) {
  int t = threadIdx.x, lane = t & 63, w = t >> 6;
  int r = blockIdx.x * 4 + w;      // global row 0..9215 (4 rows/block, same n)
  int n = r / PP;
  const __half* rp = raw + (size_t)r * PP;
  const float* scp = scale + n * PP;
  const float* lnp = lnS + n * PP;
  float m = -1e30f;
#pragma unroll
  for (int c = 0; c < 9; c++) {
    int j = c * 256 + lane * 4;
    h4 hv = *(const h4*)(rp + j);
    float4 sc = *(const float4*)(scp + j);
    float4 ls = *(const float4*)(lnp + j);
    float2 f01 = __half22float2(hv.a);
    float2 f23 = __half22float2(hv.b);
    m = fmaxf(m, fmaf(f01.x, sc.x, -ls.x));
    m = fmaxf(m, fmaf(f01.y, sc.y, -ls.y));
    m = fmaxf(m, fmaf(f23.x, sc.z, -ls.z));
    m = fmaxf(m, fmaf(f23.y, sc.w, -ls.w));
  }
  for (int o = 32; o > 0; o >>= 1) m = fmaxf(m, __shfl_down(m, o));
  __shared__ float red[4];
  if (lane == 0) red[w] = __expf(m);
  __syncthreads();
  if (t == 0)
    atomicAdd(&cxsum[n], (red[0] + red[1] + red[2] + red[3]) * (1.0f / (float)PP));
}

// Kernel 6: CX_B = -log(cxsum), loss = mean
__global__ void k_final(const float* __restrict__ cxsum, float* __restrict__ out) {
  int t = threadIdx.x;
  float cxb = 0.f;
  if (t < 4) {
    cxb = -logf(cxsum[t]);
    out[1 + t] = cxb;
  }
  for (int o = 2; o > 0; o >>= 1) cxb += __shfl_down(cxb, o);
  if (t == 0) out[0] = cxb * 0.25f;
}

extern "C" void kernel_launch(void* const* d_in, const int* in_sizes, int n_in,
                              void* d_out, int out_size, void* d_ws, size_t ws_size,
                              hipStream_t stream) {
  const float* fT = (const float*)d_in[0];
  const float* fI = (const float*)d_in[1];
  float* out = (float*)d_out;

  char* w = (char*)d_ws;
  float* meanT   = (float*)w;                                    // 1024 B
  unsigned* divu = (unsigned*)(w + 1024);                        // 36864 B
  float* S       = (float*)(w + 1024 + 36864);                   // 36864 B
  float* scale   = (float*)(w + 1024 + 2 * 36864);               // 36864 B
  float* lnS     = (float*)(w + 1024 + 3 * 36864);               // 36864 B
  float* cxsum   = (float*)(w + 1024 + 4 * 36864);               // pad to 1024
  size_t off = 1024 + 4 * 36864 + 1024;                          // 149504
  unsigned short* A = (unsigned short*)(w + off);                // 4718592 B
  unsigned short* B = (unsigned short*)(w + off + 4718592);      // 4718592 B
  __half* raw = (__half*)(w + off + 2 * 4718592);                // 42467328 B

  k_mean<<<256, 256, 0, stream>>>(fT, meanT, divu, S, cxsum);
  k_norm<<<dim3(PP / 16, NN), 256, 0, stream>>>(fT, fI, meanT, A, B);
  k_gemm<<<dim3(PP / 64, PP / 64, NN), 256, 0, stream>>>(A, B, raw, divu);
  k_colsum<<<dim3(PP / 256, NN, 4), 256, 0, stream>>>(raw, divu, S);
  k_logscale<<<36, 256, 0, stream>>>(divu, S, scale, lnS);
  k_rowmax<<<dim3(PP * NN / 4), 256, 0, stream>>>(raw, scale, lnS, cxsum);
  k_final<<<1, 64, 0, stream>>>(cxsum, out);
}

// Round 3
// 159.210 us; speedup vs baseline: 1.6696x; 1.2608x over previous
//
#include <hip/hip_runtime.h>
#include <hip/hip_fp16.h>

#define NN 4
#define CC 256
#define PP 2304   // 48*48
#define EPSV 1e-5f

typedef __attribute__((ext_vector_type(8))) short bf16x8;
typedef __attribute__((ext_vector_type(4))) float f32x4;

struct alignas(8) h4 { __half2 a, b; };

// monotone float<->uint encoding so uint atomicMin == float min (handles negatives)
__device__ inline unsigned fenc(float f) {
  unsigned b = __float_as_uint(f);
  return (b & 0x80000000u) ? ~b : (b | 0x80000000u);
}
__device__ inline float fdec(unsigned e) {
  unsigned b = (e & 0x80000000u) ? (e ^ 0x80000000u) : ~e;
  return __uint_as_float(b);
}

__device__ inline unsigned short f2bf(float x) {  // RNE float->bf16
  unsigned u = __float_as_uint(x);
  unsigned r = (u + 0x7FFFu + ((u >> 16) & 1u)) >> 16;
  return (unsigned short)r;
}

// async global->LDS, 16B per lane; LDS dest = wave-uniform base + lane*16
__device__ inline void gload_lds16(const unsigned short* g, unsigned short* l) {
  __builtin_amdgcn_global_load_lds(
      (const __attribute__((address_space(1))) void*)g,
      (__attribute__((address_space(3))) void*)l, 16, 0, 0);
}

// Kernel 1: per-channel mean of featureT over (N,H,W); also init scratch
__global__ __launch_bounds__(256) void k_mean(const float* __restrict__ fT,
                                              float* __restrict__ meanT,
                                              unsigned* __restrict__ divu,
                                              float* __restrict__ S,
                                              float* __restrict__ cxsum) {
  int c = blockIdx.x, t = threadIdx.x;
  float s = 0.f;
  for (int n = 0; n < NN; n++) {
    const float* base = fT + (size_t)n * CC * PP + (size_t)c * PP;
    for (int p = t; p < PP; p += 256) s += base[p];
  }
  for (int o = 32; o > 0; o >>= 1) s += __shfl_down(s, o);
  __shared__ float red[4];
  if ((t & 63) == 0) red[t >> 6] = s;
  __syncthreads();
  if (t == 0) meanT[c] = (red[0] + red[1] + red[2] + red[3]) / (float)(NN * PP);
  if (t < 36) {
    int idx = c * 36 + t;
    divu[idx] = 0xFFFFFFFFu;
    S[idx] = 0.f;
  }
  if (blockIdx.x == 0 && t < 4) cxsum[t] = 0.f;
}

// Kernel 2: center by meanT, l2-normalize over C, transpose to [N][P][C] bf16
__global__ __launch_bounds__(256) void k_norm(const float* __restrict__ fT,
                                              const float* __restrict__ fI,
                                              const float* __restrict__ meanT,
                                              unsigned short* __restrict__ A,
                                              unsigned short* __restrict__ B) {
  int n = blockIdx.y;
  int p0 = blockIdx.x * 16;
  int t = threadIdx.x;
  int tc = t >> 4, tp = t & 15;
  __shared__ float cT[16][257];
  __shared__ float cI[16][257];
  __shared__ float redT[16][17], redI[16][17];
  __shared__ float inv[2][16];
  float aT = 0.f, aI = 0.f;
  int p = p0 + tp;
  for (int c0 = 0; c0 < CC; c0 += 16) {
    int c = c0 + tc;
    float m = meanT[c];
    size_t g = (size_t)n * CC * PP + (size_t)c * PP + p;
    float vT = fT[g] - m;
    float vI = fI[g] - m;
    cT[tp][c] = vT; cI[tp][c] = vI;
    aT += vT * vT; aI += vI * vI;
  }
  redT[tp][tc] = aT; redI[tp][tc] = aI;
  __syncthreads();
  if (t < 16) {
    float sT = 0.f, sI = 0.f;
    for (int k = 0; k < 16; k++) { sT += redT[t][k]; sI += redI[t][k]; }
    inv[0][t] = 1.0f / sqrtf(sT);
    inv[1][t] = 1.0f / sqrtf(sI);
  }
  __syncthreads();
  for (int pp = 0; pp < 16; pp++) {
    size_t o = ((size_t)(n * PP + p0 + pp)) * CC + t;
    A[o] = f2bf(cT[pp][t] * inv[0][pp]);
    B[o] = f2bf(cI[pp][t] * inv[1][pp]);
  }
}

// Kernel 3: per-sample GEMM G = A·B^T, m97 structure: 128x128 tile, BK=64,
// global_load_lds width=16 staging, 4 waves x (4x4 16x16x32 frags).
// Writes raw=(1-G)/2 fp16; fused column-min into divu.
__global__ __launch_bounds__(256) void k_gemm(const unsigned short* __restrict__ A,
                                              const unsigned short* __restrict__ B,
                                              __half* __restrict__ raw,
                                              unsigned* __restrict__ divu) {
  int n  = blockIdx.z;
  int i0 = blockIdx.y * 128;
  int j0 = blockIdx.x * 128;
  int t  = threadIdx.x;
  int lane = t & 63;
  int w = t >> 6;
  int wi = w >> 1, wj = w & 1;           // wave quadrant (2x2 of 64x64)
  int lr = lane & 15, lq = lane >> 4;

  __shared__ unsigned short As[128 * 64];  // row-major [128][64], NO pad (global_load_lds)
  __shared__ unsigned short Bs[128 * 64];
  __shared__ unsigned cmin[128];
  if (t < 128) cmin[t] = 0xFFFFFFFFu;

  f32x4 acc[4][4];
#pragma unroll
  for (int a = 0; a < 4; a++)
#pragma unroll
    for (int b = 0; b < 4; b++) acc[a][b] = (f32x4){0.f, 0.f, 0.f, 0.f};

  const size_t baseA = ((size_t)(n * PP + i0)) * CC;
  const size_t baseB = ((size_t)(n * PP + j0)) * CC;

  for (int k0 = 0; k0 < CC; k0 += 64) {
    if (k0) __syncthreads();
    // stage 128x64 bf16 A-tile + B-tile: 1024 chunks of 16B each, 4 per lane
#pragma unroll
    for (int it = 0; it < 4; it++) {
      int chunk = (w * 4 + it) * 64 + lane;    // 0..1023
      int row = chunk >> 3, seg = chunk & 7;
      gload_lds16(A + baseA + (size_t)row * CC + k0 + seg * 8, As + (w * 4 + it) * 512);
      gload_lds16(B + baseB + (size_t)row * CC + k0 + seg * 8, Bs + (w * 4 + it) * 512);
    }
    __syncthreads();
#pragma unroll
    for (int ks = 0; ks < 2; ks++) {
      bf16x8 af[4], bf[4];
#pragma unroll
      for (int ti = 0; ti < 4; ti++)
        af[ti] = *(const bf16x8*)&As[(wi * 64 + ti * 16 + lr) * 64 + ks * 32 + lq * 8];
#pragma unroll
      for (int tj = 0; tj < 4; tj++)
        bf[tj] = *(const bf16x8*)&Bs[(wj * 64 + tj * 16 + lr) * 64 + ks * 32 + lq * 8];
#pragma unroll
      for (int ti = 0; ti < 4; ti++)
#pragma unroll
        for (int tj = 0; tj < 4; tj++)
          acc[ti][tj] = __builtin_amdgcn_mfma_f32_16x16x32_bf16(af[ti], bf[tj], acc[ti][tj], 0, 0, 0);
    }
  }

  // epilogue: C/D layout col=lane&15, row=(lane>>4)*4+reg  [m89/m91 verified]
#pragma unroll
  for (int tj = 0; tj < 4; tj++) {
    float mx = -1e30f;
    int gj = j0 + wj * 64 + tj * 16 + lr;
#pragma unroll
    for (int ti = 0; ti < 4; ti++) {
#pragma unroll
      for (int r = 0; r < 4; r++) {
        float g = acc[ti][tj][r];
        mx = fmaxf(mx, g);
        int gi = i0 + wi * 64 + ti * 16 + lq * 4 + r;
        raw[((size_t)n * PP + gi) * PP + gj] = __float2half((1.0f - g) * 0.5f);
      }
    }
    float rmin = (1.0f - mx) * 0.5f;  // min raw == (1 - max G)/2
    atomicMin(&cmin[wj * 64 + tj * 16 + lr], fenc(rmin));
  }
  __syncthreads();
  if (t < 128) atomicMin(&divu[n * PP + j0 + t], cmin[t]);
}

// Kernel 4: column sums S_j = sum_i exp(scale_j * raw[i][j]); scale from divu.
// 4 cols/lane (8B half loads), 4 waves split rows, 24 z-chunks of 96 rows.
__global__ __launch_bounds__(256) void k_colsum(const __half* __restrict__ raw,
                                                const unsigned* __restrict__ divu,
                                                float* __restrict__ S) {
  int n = blockIdx.y;
  int j0 = blockIdx.x * 256;       // 9 blocks in x
  int rz = blockIdx.z;             // 24 chunks of 96 rows
  int t = threadIdx.x;
  int lane = t & 63, w = t >> 6;
  int j = j0 + lane * 4;

  uint4 dv = *(const uint4*)(divu + n * PP + j);
  float4 sc;
  sc.x = -10.0f / (fdec(dv.x) + EPSV);
  sc.y = -10.0f / (fdec(dv.y) + EPSV);
  sc.z = -10.0f / (fdec(dv.z) + EPSV);
  sc.w = -10.0f / (fdec(dv.w) + EPSV);

  const __half* base = raw + (size_t)n * PP * PP;
  float4 s = {0.f, 0.f, 0.f, 0.f};
  int i0 = rz * 96;
  for (int i = i0 + w; i < i0 + 96; i += 4) {
    h4 hv = *(const h4*)(base + (size_t)i * PP + j);
    float2 f01 = __half22float2(hv.a);
    float2 f23 = __half22float2(hv.b);
    s.x += __expf(f01.x * sc.x);
    s.y += __expf(f01.y * sc.y);
    s.z += __expf(f23.x * sc.z);
    s.w += __expf(f23.y * sc.w);
  }
  __shared__ float4 red4[4][64];
  red4[w][lane] = s;
  __syncthreads();
  if (t < 64) {
    float4 a = red4[0][t], b = red4[1][t], c = red4[2][t], d = red4[3][t];
    int jj = j0 + t * 4;
    atomicAdd(&S[n * PP + jj + 0], a.x + b.x + c.x + d.x);
    atomicAdd(&S[n * PP + jj + 1], a.y + b.y + c.y + d.y);
    atomicAdd(&S[n * PP + jj + 2], a.z + b.z + c.z + d.z);
    atomicAdd(&S[n * PP + jj + 3], a.w + b.w + c.w + d.w);
  }
}

// Kernel 4.5: per-column scale_j and ln(S_j)
__global__ __launch_bounds__(256) void k_logscale(const unsigned* __restrict__ divu,
                                                  const float* __restrict__ S,
                                                  float* __restrict__ scale,
                                                  float* __restrict__ lnS) {
  int i = blockIdx.x * 256 + threadIdx.x;  // 36 blocks cover 9216
  float d = fdec(divu[i]);
  scale[i] = -10.0f / (d + EPSV);
  lnS[i] = logf(S[i]);
}

// Kernel 5: per-row max of (scale_j*raw - lnS_j); CX[p]=exp(max); mean into cxsum.
__global__ __launch_bounds__(256) void k_rowmax(const __half* __restrict__ raw,
                                                const float* __restrict__ scale,
                                                const float* __restrict__ lnS,
                                                float* __restrict__ cxsum) {
  int t = threadIdx.x, lane = t & 63, w = t >> 6;
  int r = blockIdx.x * 4 + w;      // global row 0..9215 (4 rows/block, same n)
  int n = r / PP;
  const __half* rp = raw + (size_t)r * PP;
  const float* scp = scale + n * PP;
  const float* lnp = lnS + n * PP;
  float m = -1e30f;
#pragma unroll
  for (int c = 0; c < 9; c++) {
    int j = c * 256 + lane * 4;
    h4 hv = *(const h4*)(rp + j);
    float4 sc = *(const float4*)(scp + j);
    float4 ls = *(const float4*)(lnp + j);
    float2 f01 = __half22float2(hv.a);
    float2 f23 = __half22float2(hv.b);
    m = fmaxf(m, fmaf(f01.x, sc.x, -ls.x));
    m = fmaxf(m, fmaf(f01.y, sc.y, -ls.y));
    m = fmaxf(m, fmaf(f23.x, sc.z, -ls.z));
    m = fmaxf(m, fmaf(f23.y, sc.w, -ls.w));
  }
  for (int o = 32; o > 0; o >>= 1) m = fmaxf(m, __shfl_down(m, o));
  __shared__ float red[4];
  if (lane == 0) red[w] = __expf(m);
  __syncthreads();
  if (t == 0)
    atomicAdd(&cxsum[n], (red[0] + red[1] + red[2] + red[3]) * (1.0f / (float)PP));
}

// Kernel 6: CX_B = -log(cxsum), loss = mean
__global__ void k_final(const float* __restrict__ cxsum, float* __restrict__ out) {
  int t = threadIdx.x;
  float cxb = 0.f;
  if (t < 4) {
    cxb = -logf(cxsum[t]);
    out[1 + t] = cxb;
  }
  for (int o = 2; o > 0; o >>= 1) cxb += __shfl_down(cxb, o);
  if (t == 0) out[0] = cxb * 0.25f;
}

extern "C" void kernel_launch(void* const* d_in, const int* in_sizes, int n_in,
                              void* d_out, int out_size, void* d_ws, size_t ws_size,
                              hipStream_t stream) {
  const float* fT = (const float*)d_in[0];
  const float* fI = (const float*)d_in[1];
  float* out = (float*)d_out;

  char* w = (char*)d_ws;
  float* meanT   = (float*)w;                                    // 1024 B
  unsigned* divu = (unsigned*)(w + 1024);                        // 36864 B
  float* S       = (float*)(w + 1024 + 36864);                   // 36864 B
  float* scale   = (float*)(w + 1024 + 2 * 36864);               // 36864 B
  float* lnS     = (float*)(w + 1024 + 3 * 36864);               // 36864 B
  float* cxsum   = (float*)(w + 1024 + 4 * 36864);               // pad to 1024
  size_t off = 1024 + 4 * 36864 + 1024;                          // 149504
  unsigned short* A = (unsigned short*)(w + off);                // 4718592 B
  unsigned short* B = (unsigned short*)(w + off + 4718592);      // 4718592 B
  __half* raw = (__half*)(w + off + 2 * 4718592);                // 42467328 B

  k_mean<<<256, 256, 0, stream>>>(fT, meanT, divu, S, cxsum);
  k_norm<<<dim3(PP / 16, NN), 256, 0, stream>>>(fT, fI, meanT, A, B);
  k_gemm<<<dim3(PP / 128, PP / 128, NN), 256, 0, stream>>>(A, B, raw, divu);
  k_colsum<<<dim3(PP / 256, NN, 24), 256, 0, stream>>>(raw, divu, S);
  k_logscale<<<36, 256, 0, stream>>>(divu, S, scale, lnS);
  k_rowmax<<<dim3(PP * NN / 4), 256, 0, stream>>>(raw, scale, lnS, cxsum);
  k_final<<<1, 64, 0, stream>>>(cxsum, out);
}

// Round 4
// 153.029 us; speedup vs baseline: 1.7370x; 1.0404x over previous
//
#include <hip/hip_runtime.h>
#include <hip/hip_fp16.h>

#define NN 4
#define CC 256
#define PP 2304   // 48*48
#define EPSV 1e-5f

typedef __attribute__((ext_vector_type(8))) short bf16x8;
typedef __attribute__((ext_vector_type(4))) float f32x4;

struct alignas(8) h4 { __half2 a, b; };

// monotone float<->uint encoding so uint atomicMin == float min (handles negatives)
__device__ inline unsigned fenc(float f) {
  unsigned b = __float_as_uint(f);
  return (b & 0x80000000u) ? ~b : (b | 0x80000000u);
}
__device__ inline float fdec(unsigned e) {
  unsigned b = (e & 0x80000000u) ? (e ^ 0x80000000u) : ~e;
  return __uint_as_float(b);
}

__device__ inline unsigned short f2bf(float x) {  // RNE float->bf16
  unsigned u = __float_as_uint(x);
  unsigned r = (u + 0x7FFFu + ((u >> 16) & 1u)) >> 16;
  return (unsigned short)r;
}

// async global->LDS, 16B per lane; LDS dest = wave-uniform base + lane*16
__device__ inline void gload_lds16(const unsigned short* g, unsigned short* l) {
  __builtin_amdgcn_global_load_lds(
      (const __attribute__((address_space(1))) void*)g,
      (__attribute__((address_space(3))) void*)l, 16, 0, 0);
}

// Kernel 0: init scratch
__global__ __launch_bounds__(256) void k_init(unsigned* __restrict__ divu,
                                              float* __restrict__ S,
                                              float* __restrict__ meanT,
                                              float* __restrict__ cxsum) {
  int i = blockIdx.x * 256 + threadIdx.x;  // 36 blocks cover 9216
  divu[i] = 0xFFFFFFFFu;
  S[i] = 0.f;
  if (i < CC) meanT[i] = 0.f;
  if (i < 4) cxsum[i] = 0.f;
}

// Kernel 1: per-channel SUM of featureT over (N,H,W) via atomics (1024 blocks)
__global__ __launch_bounds__(256) void k_mean(const float* __restrict__ fT,
                                              float* __restrict__ meanT) {
  int c = blockIdx.x, n = blockIdx.y, t = threadIdx.x;
  const float* base = fT + ((size_t)n * CC + c) * PP;
  float s = 0.f;
  for (int p = t; p < PP; p += 256) s += base[p];
  for (int o = 32; o > 0; o >>= 1) s += __shfl_down(s, o);
  __shared__ float red[4];
  if ((t & 63) == 0) red[t >> 6] = s;
  __syncthreads();
  if (t == 0) atomicAdd(&meanT[c], red[0] + red[1] + red[2] + red[3]);
}

// Kernel 2: center by meanT (sum/9216), l2-normalize over C, transpose to [N][P][C] bf16
__global__ __launch_bounds__(256) void k_norm(const float* __restrict__ fT,
                                              const float* __restrict__ fI,
                                              const float* __restrict__ meanT,
                                              unsigned short* __restrict__ A,
                                              unsigned short* __restrict__ B) {
  int n = blockIdx.y;
  int p0 = blockIdx.x * 16;
  int t = threadIdx.x;
  int tc = t >> 4, tp = t & 15;
  __shared__ float cT[16][257];
  __shared__ float cI[16][257];
  __shared__ float redT[16][17], redI[16][17];
  __shared__ float inv[2][16];
  float aT = 0.f, aI = 0.f;
  int p = p0 + tp;
  for (int c0 = 0; c0 < CC; c0 += 16) {
    int c = c0 + tc;
    float m = meanT[c] * (1.0f / (float)(NN * PP));
    size_t g = (size_t)n * CC * PP + (size_t)c * PP + p;
    float vT = fT[g] - m;
    float vI = fI[g] - m;
    cT[tp][c] = vT; cI[tp][c] = vI;
    aT += vT * vT; aI += vI * vI;
  }
  redT[tp][tc] = aT; redI[tp][tc] = aI;
  __syncthreads();
  if (t < 16) {
    float sT = 0.f, sI = 0.f;
    for (int k = 0; k < 16; k++) { sT += redT[t][k]; sI += redI[t][k]; }
    inv[0][t] = 1.0f / sqrtf(sT);
    inv[1][t] = 1.0f / sqrtf(sI);
  }
  __syncthreads();
  // vectorized output: 512 tasks of 8 channels, 16B stores
#pragma unroll
  for (int it = 0; it < 2; it++) {
    int task = it * 256 + t;
    int ps = task >> 5;       // patch 0..15
    int ch = task & 31;       // chunk of 8 channels
    float iA = inv[0][ps], iB = inv[1][ps];
    unsigned short va[8], vb[8];
#pragma unroll
    for (int e = 0; e < 8; e++) {
      va[e] = f2bf(cT[ps][ch * 8 + e] * iA);
      vb[e] = f2bf(cI[ps][ch * 8 + e] * iB);
    }
    size_t o = ((size_t)(n * PP + p0 + ps)) * CC + ch * 8;
    *(int4*)(A + o) = *(const int4*)va;
    *(int4*)(B + o) = *(const int4*)vb;
  }
}

// Kernel 3: per-sample GEMM G = A·B^T, 128x128 tile, BK=64, global_load_lds
// staging with XOR-swizzled slots (conflict-free frag reads), epilogue
// transposed through LDS for coalesced 16B raw stores; fused column-min.
__global__ __launch_bounds__(256) void k_gemm(const unsigned short* __restrict__ A,
                                              const unsigned short* __restrict__ B,
                                              __half* __restrict__ raw,
                                              unsigned* __restrict__ divu) {
  int n  = blockIdx.z;
  int i0 = blockIdx.y * 128;
  int j0 = blockIdx.x * 128;
  int t  = threadIdx.x;
  int lane = t & 63;
  int w = t >> 6;
  int wi = w >> 1, wj = w & 1;           // wave quadrant (2x2 of 64x64)
  int lr = lane & 15, lq = lane >> 4;

  // union: staging (2 x 16KB) vs epilogue fp16 tile 128x136 (34816 B)
  __shared__ __align__(16) char smem[34816];
  unsigned short* As = (unsigned short*)smem;            // slots 0..1023, 16B each
  unsigned short* Bs = (unsigned short*)(smem + 16384);
  __half* r16 = (__half*)smem;                           // [128][136]
  __shared__ unsigned cmin[128];
  if (t < 128) cmin[t] = 0xFFFFFFFFu;

  f32x4 acc[4][4];
#pragma unroll
  for (int a = 0; a < 4; a++)
#pragma unroll
    for (int b = 0; b < 4; b++) acc[a][b] = (f32x4){0.f, 0.f, 0.f, 0.f};

  const size_t baseA = ((size_t)(n * PP + i0)) * CC;
  const size_t baseB = ((size_t)(n * PP + j0)) * CC;
  // staging swizzle: slot s holds global (row = s>>3, seg = (s&7) ^ (row&7))
  int lrow8 = lane >> 3;                  // row within group-of-8
  int lseg  = (lane & 7) ^ (lrow8 & 7);   // swizzled source seg for this lane

  for (int k0 = 0; k0 < CC; k0 += 64) {
    if (k0) __syncthreads();
#pragma unroll
    for (int it = 0; it < 4; it++) {
      int sb = (w * 4 + it) * 64;               // wave-uniform slot base
      int row = (w * 4 + it) * 8 + lrow8;       // global tile row for this lane
      gload_lds16(A + baseA + (size_t)row * CC + k0 + lseg * 8, As + sb * 8);
      gload_lds16(B + baseB + (size_t)row * CC + k0 + lseg * 8, Bs + sb * 8);
    }
    __syncthreads();
#pragma unroll
    for (int ks = 0; ks < 2; ks++) {
      bf16x8 af[4], bf[4];
#pragma unroll
      for (int ti = 0; ti < 4; ti++) {
        int row = wi * 64 + ti * 16 + lr;
        int slot = row * 8 + ((ks * 4 + lq) ^ (lr & 7));
        af[ti] = *(const bf16x8*)&As[slot * 8];
      }
#pragma unroll
      for (int tj = 0; tj < 4; tj++) {
        int row = wj * 64 + tj * 16 + lr;
        int slot = row * 8 + ((ks * 4 + lq) ^ (lr & 7));
        bf[tj] = *(const bf16x8*)&Bs[slot * 8];
      }
#pragma unroll
      for (int ti = 0; ti < 4; ti++)
#pragma unroll
        for (int tj = 0; tj < 4; tj++)
          acc[ti][tj] = __builtin_amdgcn_mfma_f32_16x16x32_bf16(af[ti], bf[tj], acc[ti][tj], 0, 0, 0);
    }
  }

  __syncthreads();  // done with As/Bs; smem becomes r16
  // C/D layout col=lane&15, row=(lane>>4)*4+reg  [m89/m91 verified]
#pragma unroll
  for (int tj = 0; tj < 4; tj++) {
    float mx = -1e30f;
    int cj = wj * 64 + tj * 16 + lr;
#pragma unroll
    for (int ti = 0; ti < 4; ti++) {
#pragma unroll
      for (int r = 0; r < 4; r++) {
        float g = acc[ti][tj][r];
        mx = fmaxf(mx, g);
        int ci = wi * 64 + ti * 16 + lq * 4 + r;
        r16[ci * 136 + cj] = __float2half((1.0f - g) * 0.5f);
      }
    }
    atomicMin(&cmin[cj], fenc((1.0f - mx) * 0.5f));  // min raw == (1-max G)/2
  }
  __syncthreads();
  // coalesced writeout: 2048 chunks of 16B (8 halfs)
#pragma unroll
  for (int m = 0; m < 8; m++) {
    int chunk = m * 256 + t;
    int row = chunk >> 4, cs = chunk & 15;
    int4 v = *(const int4*)&r16[row * 136 + cs * 8];
    *(int4*)(raw + ((size_t)(n * PP + i0 + row)) * PP + j0 + cs * 8) = v;
  }
  if (t < 128) atomicMin(&divu[n * PP + j0 + t], cmin[t]);
}

// Kernel 4: column sums S_j = sum_i exp(scale_j * raw[i][j]); scale from divu.
__global__ __launch_bounds__(256) void k_colsum(const __half* __restrict__ raw,
                                                const unsigned* __restrict__ divu,
                                                float* __restrict__ S) {
  int n = blockIdx.y;
  int j0 = blockIdx.x * 256;       // 9 blocks in x
  int rz = blockIdx.z;             // 24 chunks of 96 rows
  int t = threadIdx.x;
  int lane = t & 63, w = t >> 6;
  int j = j0 + lane * 4;

  uint4 dv = *(const uint4*)(divu + n * PP + j);
  float4 sc;
  sc.x = -10.0f / (fdec(dv.x) + EPSV);
  sc.y = -10.0f / (fdec(dv.y) + EPSV);
  sc.z = -10.0f / (fdec(dv.z) + EPSV);
  sc.w = -10.0f / (fdec(dv.w) + EPSV);

  const __half* base = raw + (size_t)n * PP * PP;
  float4 s = {0.f, 0.f, 0.f, 0.f};
  int i0 = rz * 96;
  for (int i = i0 + w; i < i0 + 96; i += 4) {
    h4 hv = *(const h4*)(base + (size_t)i * PP + j);
    float2 f01 = __half22float2(hv.a);
    float2 f23 = __half22float2(hv.b);
    s.x += __expf(f01.x * sc.x);
    s.y += __expf(f01.y * sc.y);
    s.z += __expf(f23.x * sc.z);
    s.w += __expf(f23.y * sc.w);
  }
  __shared__ float4 red4[4][64];
  red4[w][lane] = s;
  __syncthreads();
  if (t < 64) {
    float4 a = red4[0][t], b = red4[1][t], c = red4[2][t], d = red4[3][t];
    int jj = j0 + t * 4;
    atomicAdd(&S[n * PP + jj + 0], a.x + b.x + c.x + d.x);
    atomicAdd(&S[n * PP + jj + 1], a.y + b.y + c.y + d.y);
    atomicAdd(&S[n * PP + jj + 2], a.z + b.z + c.z + d.z);
    atomicAdd(&S[n * PP + jj + 3], a.w + b.w + c.w + d.w);
  }
}

// Kernel 4.5: per-column scale_j and ln(S_j)
__global__ __launch_bounds__(256) void k_logscale(const unsigned* __restrict__ divu,
                                                  const float* __restrict__ S,
                                                  float* __restrict__ scale,
                                                  float* __restrict__ lnS) {
  int i = blockIdx.x * 256 + threadIdx.x;  // 36 blocks cover 9216
  float d = fdec(divu[i]);
  scale[i] = -10.0f / (d + EPSV);
  lnS[i] = logf(S[i]);
}

// Kernel 5: per-row max of (scale_j*raw - lnS_j); CX[p]=exp(max); mean into cxsum.
__global__ __launch_bounds__(256) void k_rowmax(const __half* __restrict__ raw,
                                                const float* __restrict__ scale,
                                                const float* __restrict__ lnS,
                                                float* __restrict__ cxsum) {
  int t = threadIdx.x, lane = t & 63, w = t >> 6;
  int r = blockIdx.x * 4 + w;      // global row 0..9215 (4 rows/block, same n)
  int n = r / PP;
  const __half* rp = raw + (size_t)r * PP;
  const float* scp = scale + n * PP;
  const float* lnp = lnS + n * PP;
  float m = -1e30f;
#pragma unroll
  for (int c = 0; c < 9; c++) {
    int j = c * 256 + lane * 4;
    h4 hv = *(const h4*)(rp + j);
    float4 sc = *(const float4*)(scp + j);
    float4 ls = *(const float4*)(lnp + j);
    float2 f01 = __half22float2(hv.a);
    float2 f23 = __half22float2(hv.b);
    m = fmaxf(m, fmaf(f01.x, sc.x, -ls.x));
    m = fmaxf(m, fmaf(f01.y, sc.y, -ls.y));
    m = fmaxf(m, fmaf(f23.x, sc.z, -ls.z));
    m = fmaxf(m, fmaf(f23.y, sc.w, -ls.w));
  }
  for (int o = 32; o > 0; o >>= 1) m = fmaxf(m, __shfl_down(m, o));
  __shared__ float red[4];
  if (lane == 0) red[w] = __expf(m);
  __syncthreads();
  if (t == 0)
    atomicAdd(&cxsum[n], (red[0] + red[1] + red[2] + red[3]) * (1.0f / (float)PP));
}

// Kernel 6: CX_B = -log(cxsum), loss = mean
__global__ void k_final(const float* __restrict__ cxsum, float* __restrict__ out) {
  int t = threadIdx.x;
  float cxb = 0.f;
  if (t < 4) {
    cxb = -logf(cxsum[t]);
    out[1 + t] = cxb;
  }
  for (int o = 2; o > 0; o >>= 1) cxb += __shfl_down(cxb, o);
  if (t == 0) out[0] = cxb * 0.25f;
}

extern "C" void kernel_launch(void* const* d_in, const int* in_sizes, int n_in,
                              void* d_out, int out_size, void* d_ws, size_t ws_size,
                              hipStream_t stream) {
  const float* fT = (const float*)d_in[0];
  const float* fI = (const float*)d_in[1];
  float* out = (float*)d_out;

  char* w = (char*)d_ws;
  float* meanT   = (float*)w;                                    // 1024 B
  unsigned* divu = (unsigned*)(w + 1024);                        // 36864 B
  float* S       = (float*)(w + 1024 + 36864);                   // 36864 B
  float* scale   = (float*)(w + 1024 + 2 * 36864);               // 36864 B
  float* lnS     = (float*)(w + 1024 + 3 * 36864);               // 36864 B
  float* cxsum   = (float*)(w + 1024 + 4 * 36864);               // pad to 1024
  size_t off = 1024 + 4 * 36864 + 1024;                          // 149504
  unsigned short* A = (unsigned short*)(w + off);                // 4718592 B
  unsigned short* B = (unsigned short*)(w + off + 4718592);      // 4718592 B
  __half* raw = (__half*)(w + off + 2 * 4718592);                // 42467328 B

  k_init<<<36, 256, 0, stream>>>(divu, S, meanT, cxsum);
  k_mean<<<dim3(CC, NN), 256, 0, stream>>>(fT, meanT);
  k_norm<<<dim3(PP / 16, NN), 256, 0, stream>>>(fT, fI, meanT, A, B);
  k_gemm<<<dim3(PP / 128, PP / 128, NN), 256, 0, stream>>>(A, B, raw, divu);
  k_colsum<<<dim3(PP / 256, NN, 24), 256, 0, stream>>>(raw, divu, S);
  k_logscale<<<36, 256, 0, stream>>>(divu, S, scale, lnS);
  k_rowmax<<<dim3(PP * NN / 4), 256, 0, stream>>>(raw, scale, lnS, cxsum);
  k_final<<<1, 64, 0, stream>>>(cxsum, out);
}

// Round 5
// 131.034 us; speedup vs baseline: 2.0286x; 1.1679x over previous
//
#include <hip/hip_runtime.h>
#include <hip/hip_fp16.h>

#define NN 4
#define CC 256
#define PP 2304   // 48*48
#define EPSV 1e-5f

typedef __attribute__((ext_vector_type(8))) short bf16x8;
typedef __attribute__((ext_vector_type(4))) float f32x4;

struct alignas(8) h4 { __half2 a, b; };

// monotone float<->uint encoding: uint atomicMin/Max == float min/max
__device__ inline unsigned fenc(float f) {
  unsigned b = __float_as_uint(f);
  return (b & 0x80000000u) ? ~b : (b | 0x80000000u);
}
__device__ inline float fdec(unsigned e) {
  unsigned b = (e & 0x80000000u) ? (e ^ 0x80000000u) : ~e;
  return __uint_as_float(b);
}

__device__ inline unsigned short f2bf(float x) {  // RNE float->bf16
  unsigned u = __float_as_uint(x);
  unsigned r = (u + 0x7FFFu + ((u >> 16) & 1u)) >> 16;
  return (unsigned short)r;
}

// async global->LDS, 16B per lane; LDS dest = wave-uniform base + lane*16
__device__ inline void gload_lds16(const unsigned short* g, unsigned short* l) {
  __builtin_amdgcn_global_load_lds(
      (const __attribute__((address_space(1))) void*)g,
      (__attribute__((address_space(3))) void*)l, 16, 0, 0);
}

// Kernel 1: per-channel mean of featureT over (N,H,W); inits divu/M/cxsum
__global__ __launch_bounds__(256) void k_mean(const float* __restrict__ fT,
                                              float* __restrict__ meanT,
                                              unsigned* __restrict__ divu,
                                              unsigned* __restrict__ M,
                                              float* __restrict__ cxsum) {
  int c = blockIdx.x, t = threadIdx.x;
  float s = 0.f;
  for (int n = 0; n < NN; n++) {
    const float* base = fT + (size_t)n * CC * PP + (size_t)c * PP;
    for (int p = t; p < PP; p += 256) s += base[p];
  }
  for (int o = 32; o > 0; o >>= 1) s += __shfl_down(s, o);
  __shared__ float red[4];
  if ((t & 63) == 0) red[t >> 6] = s;
  __syncthreads();
  if (t == 0) meanT[c] = (red[0] + red[1] + red[2] + red[3]) / (float)(NN * PP);
  if (t < 36) {
    int idx = c * 36 + t;
    divu[idx] = 0xFFFFFFFFu;  // encoded +inf
    M[idx] = 0u;              // encoded -max
  }
  if (blockIdx.x == 0 && t < 4) cxsum[t] = 0.f;
}

// Kernel 2: center by meanT, l2-normalize over C, transpose to [N][P][C] bf16
__global__ __launch_bounds__(256) void k_norm(const float* __restrict__ fT,
                                              const float* __restrict__ fI,
                                              const float* __restrict__ meanT,
                                              unsigned short* __restrict__ A,
                                              unsigned short* __restrict__ B) {
  int n = blockIdx.y;
  int p0 = blockIdx.x * 16;
  int t = threadIdx.x;
  int tc = t >> 4, tp = t & 15;
  __shared__ float cT[16][257];
  __shared__ float cI[16][257];
  __shared__ float redT[16][17], redI[16][17];
  __shared__ float inv[2][16];
  float aT = 0.f, aI = 0.f;
  int p = p0 + tp;
  for (int c0 = 0; c0 < CC; c0 += 16) {
    int c = c0 + tc;
    float m = meanT[c];
    size_t g = (size_t)n * CC * PP + (size_t)c * PP + p;
    float vT = fT[g] - m;
    float vI = fI[g] - m;
    cT[tp][c] = vT; cI[tp][c] = vI;
    aT += vT * vT; aI += vI * vI;
  }
  redT[tp][tc] = aT; redI[tp][tc] = aI;
  __syncthreads();
  if (t < 16) {
    float sT = 0.f, sI = 0.f;
    for (int k = 0; k < 16; k++) { sT += redT[t][k]; sI += redI[t][k]; }
    inv[0][t] = 1.0f / sqrtf(sT);
    inv[1][t] = 1.0f / sqrtf(sI);
  }
  __syncthreads();
#pragma unroll
  for (int it = 0; it < 2; it++) {
    int task = it * 256 + t;
    int ps = task >> 5;       // patch 0..15
    int ch = task & 31;       // chunk of 8 channels
    float iA = inv[0][ps], iB = inv[1][ps];
    unsigned short va[8], vb[8];
#pragma unroll
    for (int e = 0; e < 8; e++) {
      va[e] = f2bf(cT[ps][ch * 8 + e] * iA);
      vb[e] = f2bf(cI[ps][ch * 8 + e] * iB);
    }
    size_t o = ((size_t)(n * PP + p0 + ps)) * CC + ch * 8;
    *(int4*)(A + o) = *(const int4*)va;
    *(int4*)(B + o) = *(const int4*)vb;
  }
}

// Kernel 3: per-sample GEMM G = A·B^T (rows i = fT patches, cols j = fI hw).
// 128x128 tile, BK=64, global_load_lds staging w/ XOR swizzle. Epilogue writes
// TRANSPOSED raw_t[j][i] = (1-G)/2 fp16 via b64-packed LDS transpose (4 rows
// per lane are register-consecutive in C-layout) + coalesced int4 stores.
// Fused column-min (over i) -> divu[j].
__global__ __launch_bounds__(256) void k_gemm(const unsigned short* __restrict__ A,
                                              const unsigned short* __restrict__ B,
                                              __half* __restrict__ rawt,
                                              unsigned* __restrict__ divu) {
  int n  = blockIdx.z;
  int i0 = blockIdx.y * 128;
  int j0 = blockIdx.x * 128;
  int t  = threadIdx.x;
  int lane = t & 63;
  int w = t >> 6;
  int wi = w >> 1, wj = w & 1;           // wave quadrant (2x2 of 64x64)
  int lr = lane & 15, lq = lane >> 4;

  // union: staging (2 x 16KB) vs epilogue fp16 tile [128 cj][132 ci] (33792 B)
  __shared__ __align__(16) char smem[33792];
  unsigned short* As = (unsigned short*)smem;            // slots 0..1023, 16B each
  unsigned short* Bs = (unsigned short*)(smem + 16384);
  __half* r16t = (__half*)smem;                          // [128][132]
  __shared__ unsigned cmin[128];
  if (t < 128) cmin[t] = 0xFFFFFFFFu;

  f32x4 acc[4][4];
#pragma unroll
  for (int a = 0; a < 4; a++)
#pragma unroll
    for (int b = 0; b < 4; b++) acc[a][b] = (f32x4){0.f, 0.f, 0.f, 0.f};

  const size_t baseA = ((size_t)(n * PP + i0)) * CC;
  const size_t baseB = ((size_t)(n * PP + j0)) * CC;
  int lrow8 = lane >> 3;
  int lseg  = (lane & 7) ^ (lrow8 & 7);   // XOR-swizzled source seg

  for (int k0 = 0; k0 < CC; k0 += 64) {
    if (k0) __syncthreads();
#pragma unroll
    for (int it = 0; it < 4; it++) {
      int sb = (w * 4 + it) * 64;
      int row = (w * 4 + it) * 8 + lrow8;
      gload_lds16(A + baseA + (size_t)row * CC + k0 + lseg * 8, As + sb * 8);
      gload_lds16(B + baseB + (size_t)row * CC + k0 + lseg * 8, Bs + sb * 8);
    }
    __syncthreads();
#pragma unroll
    for (int ks = 0; ks < 2; ks++) {
      bf16x8 af[4], bf[4];
#pragma unroll
      for (int ti = 0; ti < 4; ti++) {
        int row = wi * 64 + ti * 16 + lr;
        int slot = row * 8 + ((ks * 4 + lq) ^ (lr & 7));
        af[ti] = *(const bf16x8*)&As[slot * 8];
      }
#pragma unroll
      for (int tj = 0; tj < 4; tj++) {
        int row = wj * 64 + tj * 16 + lr;
        int slot = row * 8 + ((ks * 4 + lq) ^ (lr & 7));
        bf[tj] = *(const bf16x8*)&Bs[slot * 8];
      }
#pragma unroll
      for (int ti = 0; ti < 4; ti++)
#pragma unroll
        for (int tj = 0; tj < 4; tj++)
          acc[ti][tj] = __builtin_amdgcn_mfma_f32_16x16x32_bf16(af[ti], bf[tj], acc[ti][tj], 0, 0, 0);
    }
  }

  __syncthreads();  // done with As/Bs; smem becomes r16t
  // C/D layout col=lane&15, row=(lane>>4)*4+reg  [m89/m91 verified]
#pragma unroll
  for (int tj = 0; tj < 4; tj++) {
    float mx = -1e30f;
    int cj = wj * 64 + tj * 16 + lr;
#pragma unroll
    for (int ti = 0; ti < 4; ti++) {
      alignas(8) unsigned short pk[4];
#pragma unroll
      for (int r = 0; r < 4; r++) {
        float g = acc[ti][tj][r];
        mx = fmaxf(mx, g);
        pk[r] = __half_as_ushort(__float2half((1.0f - g) * 0.5f));
      }
      int ci = wi * 64 + ti * 16 + lq * 4;
      *(short4*)&r16t[cj * 132 + ci] = *(const short4*)pk;  // b64, conflict-free
    }
    atomicMin(&cmin[cj], fenc((1.0f - mx) * 0.5f));  // min raw == (1-max G)/2
  }
  __syncthreads();
  // coalesced writeout of raw_t rows (j-major): 2048 chunks of 8 halfs
#pragma unroll
  for (int m = 0; m < 8; m++) {
    int chunk = m * 256 + t;
    int row = chunk >> 4, cs = chunk & 15;    // row=cj, cs=8-half chunk of ci
    int2 lo = *(const int2*)&r16t[row * 132 + cs * 8];
    int2 hi = *(const int2*)&r16t[row * 132 + cs * 8 + 4];
    int4 v = {lo.x, lo.y, hi.x, hi.y};
    *(int4*)(rawt + ((size_t)(n * PP + j0 + row)) * PP + i0 + cs * 8) = v;
  }
  if (t < 128) atomicMin(&divu[n * PP + j0 + t], cmin[t]);
}

// Kernel 4: S_j = sum_i exp(sc_j * raw_t[j][i]) — contiguous row reduce,
// one wave per j-row, wave-uniform sc_j, no atomics.
__global__ __launch_bounds__(256) void k_colsum(const __half* __restrict__ rawt,
                                                const unsigned* __restrict__ divu,
                                                float* __restrict__ S) {
  int t = threadIdx.x, lane = t & 63, w = t >> 6;
  int r = blockIdx.x * 4 + w;      // global j-row 0..9215
  float d = fdec(divu[r]);
  float sc = -10.0f / (d + EPSV);
  const __half* rp = rawt + (size_t)r * PP;
  float s = 0.f;
#pragma unroll
  for (int c = 0; c < 9; c++) {
    h4 hv = *(const h4*)(rp + c * 256 + lane * 4);
    float2 f01 = __half22float2(hv.a);
    float2 f23 = __half22float2(hv.b);
    s += __expf(f01.x * sc) + __expf(f01.y * sc) + __expf(f23.x * sc) + __expf(f23.y * sc);
  }
  for (int o = 32; o > 0; o >>= 1) s += __shfl_down(s, o);
  if (lane == 0) S[r] = s;
}

// Kernel 4.5: per-column scale_j and ln(S_j)
__global__ __launch_bounds__(256) void k_logscale(const unsigned* __restrict__ divu,
                                                  const float* __restrict__ S,
                                                  float* __restrict__ scale,
                                                  float* __restrict__ lnS) {
  int i = blockIdx.x * 256 + threadIdx.x;  // 36 blocks cover 9216
  float d = fdec(divu[i]);
  scale[i] = -10.0f / (d + EPSV);
  lnS[i] = logf(S[i]);
}

// Kernel 5: M_i = max_j (sc_j*raw_t[j][i] - lnS_j) — strided pass over j-rows;
// sc_j/lnS_j wave-uniform per row; partial max -> encoded atomicMax into M.
__global__ __launch_bounds__(256) void k_rowmax(const __half* __restrict__ rawt,
                                                const float* __restrict__ scale,
                                                const float* __restrict__ lnS,
                                                unsigned* __restrict__ M) {
  int n = blockIdx.y;
  int i0 = blockIdx.x * 256;       // 9 blocks in x
  int rz = blockIdx.z;             // 24 chunks of 96 j-rows
  int t = threadIdx.x;
  int lane = t & 63, w = t >> 6;
  int i = i0 + lane * 4;

  float4 m = {-1e30f, -1e30f, -1e30f, -1e30f};
  int j0 = rz * 96;
  for (int j = j0 + w; j < j0 + 96; j += 4) {
    float scj = scale[n * PP + j];   // wave-uniform broadcast
    float lsj = lnS[n * PP + j];
    h4 hv = *(const h4*)(rawt + ((size_t)(n * PP + j)) * PP + i);
    float2 f01 = __half22float2(hv.a);
    float2 f23 = __half22float2(hv.b);
    m.x = fmaxf(m.x, fmaf(f01.x, scj, -lsj));
    m.y = fmaxf(m.y, fmaf(f01.y, scj, -lsj));
    m.z = fmaxf(m.z, fmaf(f23.x, scj, -lsj));
    m.w = fmaxf(m.w, fmaf(f23.y, scj, -lsj));
  }
  __shared__ float4 red4[4][64];
  red4[w][lane] = m;
  __syncthreads();
  if (t < 64) {
    float4 a = red4[0][t], b = red4[1][t], c = red4[2][t], d = red4[3][t];
    int ii = i0 + t * 4;
    atomicMax(&M[n * PP + ii + 0], fenc(fmaxf(fmaxf(a.x, b.x), fmaxf(c.x, d.x))));
    atomicMax(&M[n * PP + ii + 1], fenc(fmaxf(fmaxf(a.y, b.y), fmaxf(c.y, d.y))));
    atomicMax(&M[n * PP + ii + 2], fenc(fmaxf(fmaxf(a.z, b.z), fmaxf(c.z, d.z))));
    atomicMax(&M[n * PP + ii + 3], fenc(fmaxf(fmaxf(a.w, b.w), fmaxf(c.w, d.w))));
  }
}

// Kernel 5.5: CX[p] = exp(M_p); mean over p per sample -> cxsum[n]
__global__ __launch_bounds__(256) void k_cx(const unsigned* __restrict__ M,
                                            float* __restrict__ cxsum) {
  int b = blockIdx.x, t = threadIdx.x;
  int idx = b * 256 + t;           // 36 blocks; each block within one n (256 | 2304)
  int n = idx / PP;
  float v = __expf(fdec(M[idx])) * (1.0f / (float)PP);
  for (int o = 32; o > 0; o >>= 1) v += __shfl_down(v, o);
  __shared__ float red[4];
  if ((t & 63) == 0) red[t >> 6] = v;
  __syncthreads();
  if (t == 0) atomicAdd(&cxsum[n], red[0] + red[1] + red[2] + red[3]);
}

// Kernel 6: CX_B = -log(cxsum), loss = mean
__global__ void k_final(const float* __restrict__ cxsum, float* __restrict__ out) {
  int t = threadIdx.x;
  float cxb = 0.f;
  if (t < 4) {
    cxb = -logf(cxsum[t]);
    out[1 + t] = cxb;
  }
  for (int o = 2; o > 0; o >>= 1) cxb += __shfl_down(cxb, o);
  if (t == 0) out[0] = cxb * 0.25f;
}

extern "C" void kernel_launch(void* const* d_in, const int* in_sizes, int n_in,
                              void* d_out, int out_size, void* d_ws, size_t ws_size,
                              hipStream_t stream) {
  const float* fT = (const float*)d_in[0];
  const float* fI = (const float*)d_in[1];
  float* out = (float*)d_out;

  char* w = (char*)d_ws;
  float* meanT   = (float*)w;                                    // 1024 B
  unsigned* divu = (unsigned*)(w + 1024);                        // 36864 B
  float* S       = (float*)(w + 1024 + 36864);                   // 36864 B
  float* scale   = (float*)(w + 1024 + 2 * 36864);               // 36864 B
  float* lnS     = (float*)(w + 1024 + 3 * 36864);               // 36864 B
  unsigned* M    = (unsigned*)(w + 1024 + 4 * 36864);            // 36864 B
  float* cxsum   = (float*)(w + 1024 + 5 * 36864);               // pad to 1024
  size_t off = 1024 + 5 * 36864 + 1024;                          // 186368
  unsigned short* A = (unsigned short*)(w + off);                // 4718592 B
  unsigned short* B = (unsigned short*)(w + off + 4718592);      // 4718592 B
  __half* rawt = (__half*)(w + off + 2 * 4718592);               // 42467328 B

  k_mean<<<256, 256, 0, stream>>>(fT, meanT, divu, M, cxsum);
  k_norm<<<dim3(PP / 16, NN), 256, 0, stream>>>(fT, fI, meanT, A, B);
  k_gemm<<<dim3(PP / 128, PP / 128, NN), 256, 0, stream>>>(A, B, rawt, divu);
  k_colsum<<<dim3(PP * NN / 4), 256, 0, stream>>>(rawt, divu, S);
  k_logscale<<<36, 256, 0, stream>>>(divu, S, scale, lnS);
  k_rowmax<<<dim3(PP / 256, NN, 24), 256, 0, stream>>>(rawt, scale, lnS, M);
  k_cx<<<36, 256, 0, stream>>>(M, cxsum);
  k_final<<<1, 64, 0, stream>>>(cxsum, out);
}

// Round 6
// 126.629 us; speedup vs baseline: 2.0991x; 1.0348x over previous
//
#include <hip/hip_runtime.h>
#include <hip/hip_fp16.h>

#define NN 4
#define CC 256
#define PP 2304   // 48*48
#define EPSV 1e-5f

typedef __attribute__((ext_vector_type(8))) short bf16x8;
typedef __attribute__((ext_vector_type(4))) float f32x4;

struct alignas(8) h4 { __half2 a, b; };

// monotone float<->uint encoding: uint atomicMin/Max == float min/max
__device__ inline unsigned fenc(float f) {
  unsigned b = __float_as_uint(f);
  return (b & 0x80000000u) ? ~b : (b | 0x80000000u);
}
__device__ inline float fdec(unsigned e) {
  unsigned b = (e & 0x80000000u) ? (e ^ 0x80000000u) : ~e;
  return __uint_as_float(b);
}

__device__ inline unsigned short f2bf(float x) {  // RNE float->bf16
  unsigned u = __float_as_uint(x);
  unsigned r = (u + 0x7FFFu + ((u >> 16) & 1u)) >> 16;
  return (unsigned short)r;
}

// async global->LDS, 16B per lane; LDS dest = wave-uniform base + lane*16
__device__ inline void gload_lds16(const unsigned short* g, unsigned short* l) {
  __builtin_amdgcn_global_load_lds(
      (const __attribute__((address_space(1))) void*)g,
      (__attribute__((address_space(3))) void*)l, 16, 0, 0);
}

// Kernel 1: per-(c,n) partial channel sums of fT (float4 loads, no atomics);
// inits divu/cxsum. k_norm combines the 4 partials per channel.
__global__ __launch_bounds__(256) void k_mean(const float* __restrict__ fT,
                                              float* __restrict__ partial,
                                              unsigned* __restrict__ divu,
                                              float* __restrict__ cxsum) {
  int c = blockIdx.x, n = blockIdx.y, t = threadIdx.x;
  const float4* base = (const float4*)(fT + ((size_t)n * CC + c) * PP);  // 576 float4
  float s = 0.f;
  for (int k = t; k < 576; k += 256) {
    float4 v = base[k];
    s += (v.x + v.y) + (v.z + v.w);
  }
  for (int o = 32; o > 0; o >>= 1) s += __shfl_down(s, o);
  __shared__ float red[4];
  if ((t & 63) == 0) red[t >> 6] = s;
  __syncthreads();
  if (t == 0) partial[c * NN + n] = red[0] + red[1] + red[2] + red[3];
  if (n == 0 && t < 36) divu[c * 36 + t] = 0xFFFFFFFFu;  // encoded +inf
  if (n == 0 && c == 0 && t < 4) cxsum[t] = 0.f;
}

// Kernel 2: center by mean (combined from partials), l2-normalize over C,
// transpose to [N][P][C] bf16. float4 global loads along p.
__global__ __launch_bounds__(256) void k_norm(const float* __restrict__ fT,
                                              const float* __restrict__ fI,
                                              const float* __restrict__ partial,
                                              unsigned short* __restrict__ A,
                                              unsigned short* __restrict__ B) {
  int n = blockIdx.y;
  int p0 = blockIdx.x * 16;
  int t = threadIdx.x;
  int pq = (t & 3) * 4;   // p-quad base 0,4,8,12
  int cg = t >> 2;        // c-group 0..63
  __shared__ float cT[16][257];
  __shared__ float cI[16][257];
  __shared__ float redf[2][16][65];
  __shared__ float inv[2][16];
  float aT[4] = {0.f, 0.f, 0.f, 0.f}, aI[4] = {0.f, 0.f, 0.f, 0.f};
#pragma unroll
  for (int ph = 0; ph < 4; ph++) {
    int c = ph * 64 + cg;
    float m = (partial[c * NN + 0] + partial[c * NN + 1] +
               partial[c * NN + 2] + partial[c * NN + 3]) * (1.0f / (float)(NN * PP));
    size_t g = ((size_t)n * CC + c) * PP + p0 + pq;
    float4 vT = *(const float4*)(fT + g);
    float4 vI = *(const float4*)(fI + g);
    float xT[4] = {vT.x - m, vT.y - m, vT.z - m, vT.w - m};
    float xI[4] = {vI.x - m, vI.y - m, vI.z - m, vI.w - m};
#pragma unroll
    for (int k = 0; k < 4; k++) {
      cT[pq + k][c] = xT[k]; cI[pq + k][c] = xI[k];
      aT[k] += xT[k] * xT[k]; aI[k] += xI[k] * xI[k];
    }
  }
#pragma unroll
  for (int k = 0; k < 4; k++) {
    redf[0][pq + k][cg] = aT[k];
    redf[1][pq + k][cg] = aI[k];
  }
  __syncthreads();
  if (t < 32) {
    int which = t >> 4, p = t & 15;
    float s = 0.f;
    for (int g = 0; g < 64; g++) s += redf[which][p][g];
    inv[which][p] = 1.0f / sqrtf(s);
  }
  __syncthreads();
#pragma unroll
  for (int it = 0; it < 2; it++) {
    int task = it * 256 + t;
    int ps = task >> 5;       // patch 0..15
    int ch = task & 31;       // chunk of 8 channels
    float iA = inv[0][ps], iB = inv[1][ps];
    unsigned short va[8], vb[8];
#pragma unroll
    for (int e = 0; e < 8; e++) {
      va[e] = f2bf(cT[ps][ch * 8 + e] * iA);
      vb[e] = f2bf(cI[ps][ch * 8 + e] * iB);
    }
    size_t o = ((size_t)(n * PP + p0 + ps)) * CC + ch * 8;
    *(int4*)(A + o) = *(const int4*)va;
    *(int4*)(B + o) = *(const int4*)vb;
  }
}

// Kernel 3: per-sample GEMM G = A·B^T, 128x128 tile, BK=64, global_load_lds
// staging w/ XOR swizzle. Epilogue writes TRANSPOSED raw_t[j][i]=(1-G)/2 fp16
// via b64-packed LDS transpose + coalesced int4 stores; fused col-min -> divu.
__global__ __launch_bounds__(256) void k_gemm(const unsigned short* __restrict__ A,
                                              const unsigned short* __restrict__ B,
                                              __half* __restrict__ rawt,
                                              unsigned* __restrict__ divu) {
  int n  = blockIdx.z;
  int i0 = blockIdx.y * 128;
  int j0 = blockIdx.x * 128;
  int t  = threadIdx.x;
  int lane = t & 63;
  int w = t >> 6;
  int wi = w >> 1, wj = w & 1;           // wave quadrant (2x2 of 64x64)
  int lr = lane & 15, lq = lane >> 4;

  __shared__ __align__(16) char smem[33792];
  unsigned short* As = (unsigned short*)smem;            // slots 0..1023, 16B each
  unsigned short* Bs = (unsigned short*)(smem + 16384);
  __half* r16t = (__half*)smem;                          // [128][132]
  __shared__ unsigned cmin[128];
  if (t < 128) cmin[t] = 0xFFFFFFFFu;

  f32x4 acc[4][4];
#pragma unroll
  for (int a = 0; a < 4; a++)
#pragma unroll
    for (int b = 0; b < 4; b++) acc[a][b] = (f32x4){0.f, 0.f, 0.f, 0.f};

  const size_t baseA = ((size_t)(n * PP + i0)) * CC;
  const size_t baseB = ((size_t)(n * PP + j0)) * CC;
  int lrow8 = lane >> 3;
  int lseg  = (lane & 7) ^ (lrow8 & 7);   // XOR-swizzled source seg

  for (int k0 = 0; k0 < CC; k0 += 64) {
    if (k0) __syncthreads();
#pragma unroll
    for (int it = 0; it < 4; it++) {
      int sb = (w * 4 + it) * 64;
      int row = (w * 4 + it) * 8 + lrow8;
      gload_lds16(A + baseA + (size_t)row * CC + k0 + lseg * 8, As + sb * 8);
      gload_lds16(B + baseB + (size_t)row * CC + k0 + lseg * 8, Bs + sb * 8);
    }
    __syncthreads();
#pragma unroll
    for (int ks = 0; ks < 2; ks++) {
      bf16x8 af[4], bf[4];
#pragma unroll
      for (int ti = 0; ti < 4; ti++) {
        int row = wi * 64 + ti * 16 + lr;
        int slot = row * 8 + ((ks * 4 + lq) ^ (lr & 7));
        af[ti] = *(const bf16x8*)&As[slot * 8];
      }
#pragma unroll
      for (int tj = 0; tj < 4; tj++) {
        int row = wj * 64 + tj * 16 + lr;
        int slot = row * 8 + ((ks * 4 + lq) ^ (lr & 7));
        bf[tj] = *(const bf16x8*)&Bs[slot * 8];
      }
#pragma unroll
      for (int ti = 0; ti < 4; ti++)
#pragma unroll
        for (int tj = 0; tj < 4; tj++)
          acc[ti][tj] = __builtin_amdgcn_mfma_f32_16x16x32_bf16(af[ti], bf[tj], acc[ti][tj], 0, 0, 0);
    }
  }

  __syncthreads();  // done with As/Bs; smem becomes r16t
  // C/D layout col=lane&15, row=(lane>>4)*4+reg  [m89/m91 verified]
#pragma unroll
  for (int tj = 0; tj < 4; tj++) {
    float mx = -1e30f;
    int cj = wj * 64 + tj * 16 + lr;
#pragma unroll
    for (int ti = 0; ti < 4; ti++) {
      alignas(8) unsigned short pk[4];
#pragma unroll
      for (int r = 0; r < 4; r++) {
        float g = acc[ti][tj][r];
        mx = fmaxf(mx, g);
        pk[r] = __half_as_ushort(__float2half((1.0f - g) * 0.5f));
      }
      int ci = wi * 64 + ti * 16 + lq * 4;
      *(short4*)&r16t[cj * 132 + ci] = *(const short4*)pk;  // b64, conflict-free
    }
    atomicMin(&cmin[cj], fenc((1.0f - mx) * 0.5f));  // min raw == (1-max G)/2
  }
  __syncthreads();
#pragma unroll
  for (int m = 0; m < 8; m++) {
    int chunk = m * 256 + t;
    int row = chunk >> 4, cs = chunk & 15;
    int2 lo = *(const int2*)&r16t[row * 132 + cs * 8];
    int2 hi = *(const int2*)&r16t[row * 132 + cs * 8 + 4];
    int4 v = {lo.x, lo.y, hi.x, hi.y};
    *(int4*)(rawt + ((size_t)(n * PP + j0 + row)) * PP + i0 + cs * 8) = v;
  }
  if (t < 128) atomicMin(&divu[n * PP + j0 + t], cmin[t]);
}

// Kernel 4: per j-row: S = sum_i exp(sc_j*raw_t[j][i]); writes scale_j and
// lnS_j directly (logscale fused). One wave per row, wave-uniform sc_j.
__global__ __launch_bounds__(256) void k_colsum(const __half* __restrict__ rawt,
                                                const unsigned* __restrict__ divu,
                                                float* __restrict__ scale,
                                                float* __restrict__ lnS) {
  int t = threadIdx.x, lane = t & 63, w = t >> 6;
  int r = blockIdx.x * 4 + w;      // global j-row 0..9215
  float d = fdec(divu[r]);
  float sc = -10.0f / (d + EPSV);
  const __half* rp = rawt + (size_t)r * PP;
  float s = 0.f;
#pragma unroll
  for (int c = 0; c < 9; c++) {
    h4 hv = *(const h4*)(rp + c * 256 + lane * 4);
    float2 f01 = __half22float2(hv.a);
    float2 f23 = __half22float2(hv.b);
    s += __expf(f01.x * sc) + __expf(f01.y * sc) + __expf(f23.x * sc) + __expf(f23.y * sc);
  }
  for (int o = 32; o > 0; o >>= 1) s += __shfl_down(s, o);
  if (lane == 0) {
    scale[r] = sc;
    lnS[r] = logf(s);
  }
}

// Kernel 5 (fused w/ k_cx): each block owns 32 i's x ALL j. M_i completes
// in-block -> exp + reduce -> one atomicAdd to cxsum[n]. Block=512 (8 waves),
// q=t&7 picks i-quad, g=t>>3 picks j-group; sc_j/lnS_j uniform per group.
__global__ __launch_bounds__(512) void k_rowmax(const __half* __restrict__ rawt,
                                                const float* __restrict__ scale,
                                                const float* __restrict__ lnS,
                                                float* __restrict__ cxsum) {
  int n = blockIdx.y;
  int i0 = blockIdx.x * 32;
  int t = threadIdx.x, lane = t & 63, w = t >> 6;
  int q = t & 7, g = t >> 3;       // i-quad 0..7, j-group 0..63
  int i = i0 + q * 4;
  const float* scp = scale + n * PP;
  const float* lnp = lnS + n * PP;
  float m0 = -1e30f, m1 = -1e30f, m2 = -1e30f, m3 = -1e30f;
#pragma unroll 4
  for (int it = 0; it < 36; it++) {
    int j = it * 64 + g;
    float scj = scp[j], lsj = lnp[j];
    h4 hv = *(const h4*)(rawt + ((size_t)(n * PP + j)) * PP + i);
    float2 f01 = __half22float2(hv.a);
    float2 f23 = __half22float2(hv.b);
    m0 = fmaxf(m0, fmaf(f01.x, scj, -lsj));
    m1 = fmaxf(m1, fmaf(f01.y, scj, -lsj));
    m2 = fmaxf(m2, fmaf(f23.x, scj, -lsj));
    m3 = fmaxf(m3, fmaf(f23.y, scj, -lsj));
  }
  // butterfly over j-group bits within wave (bits 3..5 of lane)
#pragma unroll
  for (int o = 8; o <= 32; o <<= 1) {
    m0 = fmaxf(m0, __shfl_xor(m0, o));
    m1 = fmaxf(m1, __shfl_xor(m1, o));
    m2 = fmaxf(m2, __shfl_xor(m2, o));
    m3 = fmaxf(m3, __shfl_xor(m3, o));
  }
  __shared__ float4 red[8][8];
  if (lane < 8) red[w][lane] = (float4){m0, m1, m2, m3};
  __syncthreads();
  if (t < 8) {
    float4 a = red[0][t];
#pragma unroll
    for (int ww = 1; ww < 8; ww++) {
      float4 b = red[ww][t];
      a.x = fmaxf(a.x, b.x); a.y = fmaxf(a.y, b.y);
      a.z = fmaxf(a.z, b.z); a.w = fmaxf(a.w, b.w);
    }
    float v = (__expf(a.x) + __expf(a.y) + __expf(a.z) + __expf(a.w)) * (1.0f / (float)PP);
    v += __shfl_down(v, 4);
    v += __shfl_down(v, 2);
    v += __shfl_down(v, 1);
    if (t == 0) atomicAdd(&cxsum[n], v);
  }
}

// Kernel 6: CX_B = -log(cxsum), loss = mean
__global__ void k_final(const float* __restrict__ cxsum, float* __restrict__ out) {
  int t = threadIdx.x;
  float cxb = 0.f;
  if (t < 4) {
    cxb = -logf(cxsum[t]);
    out[1 + t] = cxb;
  }
  for (int o = 2; o > 0; o >>= 1) cxb += __shfl_down(cxb, o);
  if (t == 0) out[0] = cxb * 0.25f;
}

extern "C" void kernel_launch(void* const* d_in, const int* in_sizes, int n_in,
                              void* d_out, int out_size, void* d_ws, size_t ws_size,
                              hipStream_t stream) {
  const float* fT = (const float*)d_in[0];
  const float* fI = (const float*)d_in[1];
  float* out = (float*)d_out;

  char* w = (char*)d_ws;
  float* partial = (float*)w;                                    // 4096 B
  unsigned* divu = (unsigned*)(w + 4096);                        // 36864 B
  float* scale   = (float*)(w + 4096 + 36864);                   // 36864 B
  float* lnS     = (float*)(w + 4096 + 2 * 36864);               // 36864 B
  float* cxsum   = (float*)(w + 4096 + 3 * 36864);               // pad to 1024
  size_t off = 4096 + 3 * 36864 + 1024;                          // 115712
  unsigned short* A = (unsigned short*)(w + off);                // 4718592 B
  unsigned short* B = (unsigned short*)(w + off + 4718592);      // 4718592 B
  __half* rawt = (__half*)(w + off + 2 * 4718592);               // 42467328 B

  k_mean<<<dim3(CC, NN), 256, 0, stream>>>(fT, partial, divu, cxsum);
  k_norm<<<dim3(PP / 16, NN), 256, 0, stream>>>(fT, fI, partial, A, B);
  k_gemm<<<dim3(PP / 128, PP / 128, NN), 256, 0, stream>>>(A, B, rawt, divu);
  k_colsum<<<dim3(PP * NN / 4), 256, 0, stream>>>(rawt, divu, scale, lnS);
  k_rowmax<<<dim3(PP / 32, NN), 512, 0, stream>>>(rawt, scale, lnS, cxsum);
  k_final<<<1, 64, 0, stream>>>(cxsum, out);
}